// Round 2
// baseline (1465.150 us; speedup 1.0000x reference)
//
#include <hip/hip_runtime.h>
#include <hip/hip_bf16.h>
#include <stdint.h>

// Problem dims
#define B_SZ 32
#define T_SZ 512
#define I_SZ 1024
#define H_SZ 8
#define HS_SZ 128

typedef __attribute__((ext_vector_type(8))) short short8;
typedef __attribute__((ext_vector_type(4))) float f32x4;

// ---------------- fp32 <-> bf16 helpers ----------------
static __device__ __forceinline__ unsigned short f2bf(float f) {
  union { float f; unsigned int u; } c; c.f = f;
  unsigned int u = c.u;
  unsigned int r = (u + 0x7fffu + ((u >> 16) & 1u)) >> 16;
  return (unsigned short)r;
}
static __device__ __forceinline__ float bf2f(unsigned short s) {
  union { unsigned int u; float f; } c; c.u = ((unsigned int)s) << 16;
  return c.f;
}
// split x into hi (bf16) + lo (bf16 of residual)
static __device__ __forceinline__ void split2(float x, unsigned short& hi,
                                              unsigned short& lo) {
  hi = f2bf(x);
  lo = f2bf(x - bf2f(hi));
}

__global__ void conv_x_split(const float* __restrict__ x,
                             unsigned short* __restrict__ ohi,
                             unsigned short* __restrict__ olo, int n4) {
  int i = blockIdx.x * blockDim.x + threadIdx.x;
  if (i >= n4) return;
  float4 v = ((const float4*)x)[i];
  ushort4 h, l;
  split2(v.x, h.x, l.x);
  split2(v.y, h.y, l.y);
  split2(v.z, h.z, l.z);
  split2(v.w, h.w, l.w);
  ((ushort4*)ohi)[i] = h;
  ((ushort4*)olo)[i] = l;
}

// Combined weight Wc[4096][1024], row n = h*512 + k4:
//   k4 in [0,256)   -> weight_if[h][k4][:]      (i rows then f rows)
//   k4 in [256,512) -> weight_zo[h][k4-256][:]  (z rows then o rows)
__global__ void conv_w_split(const float* __restrict__ wif,
                             const float* __restrict__ wzo,
                             unsigned short* __restrict__ ohi,
                             unsigned short* __restrict__ olo) {
  int i = blockIdx.x * blockDim.x + threadIdx.x;  // float4 index
  int flat = i * 4;
  int n = flat >> 10;
  int col = flat & 1023;
  int h = n >> 9, k4 = n & 511;
  const float* src = (k4 < 256)
                         ? (wif + ((size_t)(h * 256 + k4) * 1024 + col))
                         : (wzo + ((size_t)(h * 256 + (k4 - 256)) * 1024 + col));
  float4 v = *(const float4*)src;
  ushort4 hh, ll;
  split2(v.x, hh.x, ll.x);
  split2(v.y, hh.y, ll.y);
  split2(v.z, hh.z, ll.z);
  split2(v.w, hh.w, ll.w);
  ((ushort4*)ohi)[i] = hh;
  ((ushort4*)olo)[i] = ll;
}

// ---------------- GEMM (3-pass split bf16 = emulated fp32) ----------------
// G[32*tch x 4096] = A_chunk[32*tch x 1024] * Wc^T, acc += AhWh + AhWl + AlWh.
// 128x128 tile, BK=32, 4 waves (2x2), 4x4 16x16x32 frags per wave,
// global_load_lds width=16 staging, 2 barriers per K-step.
__device__ __forceinline__ void gld_lds16(const void* g, void* l) {
  __builtin_amdgcn_global_load_lds(
      (const __attribute__((address_space(1))) void*)g,
      (__attribute__((address_space(3))) void*)l, 16, 0, 0);
}

__global__ __launch_bounds__(256)
void gemm3_kernel(const unsigned short* __restrict__ Ahi,
                  const unsigned short* __restrict__ Alo,
                  const unsigned short* __restrict__ Whi,
                  const unsigned short* __restrict__ Wlo,
                  float* __restrict__ G, int t0, int ltch) {
  __shared__ short AH[128 * 32];
  __shared__ short AL[128 * 32];
  __shared__ short WH[128 * 32];
  __shared__ short WL[128 * 32];

  int tid = threadIdx.x;
  int lane = tid & 63, wave = tid >> 6;
  int wm = wave >> 1, wn = wave & 1;
  int bx = blockIdx.x, by = blockIdx.y;
  int l15 = lane & 15, kg = lane >> 4;
  int tchm = (1 << ltch) - 1;

  f32x4 zero4 = {0.f, 0.f, 0.f, 0.f};
  f32x4 acc[4][4];
#pragma unroll
  for (int mi = 0; mi < 4; ++mi)
#pragma unroll
    for (int ni = 0; ni < 4; ++ni) acc[mi][ni] = zero4;

  // staging unit u in [0,512), 16B each; lds short offset = u*8
  int u0 = wave * 128 + lane;
  int u1 = u0 + 64;
  // chunk row r -> global xs row: b = r>>ltch, m = r&tchm, row = b*512+t0+m
  int r0 = bx * 128 + (u0 >> 2);
  int r1 = bx * 128 + (u1 >> 2);
  size_t arow0 = (size_t)(r0 >> ltch) * 512 + t0 + (r0 & tchm);
  size_t arow1 = (size_t)(r1 >> ltch) * 512 + t0 + (r1 & tchm);
  size_t aoff0 = arow0 * 1024 + (u0 & 3) * 8;
  size_t aoff1 = arow1 * 1024 + (u1 & 3) * 8;
  size_t woff0 = (size_t)(by * 128 + (u0 >> 2)) * 1024 + (u0 & 3) * 8;
  size_t woff1 = (size_t)(by * 128 + (u1 >> 2)) * 1024 + (u1 & 3) * 8;

  short* ah_d0 = &AH[wave * 1024];
  short* ah_d1 = &AH[wave * 1024 + 512];
  short* al_d0 = &AL[wave * 1024];
  short* al_d1 = &AL[wave * 1024 + 512];
  short* wh_d0 = &WH[wave * 1024];
  short* wh_d1 = &WH[wave * 1024 + 512];
  short* wl_d0 = &WL[wave * 1024];
  short* wl_d1 = &WL[wave * 1024 + 512];

  for (int k0 = 0; k0 < 1024; k0 += 32) {
    __syncthreads();  // previous compute done before overwrite
    gld_lds16(Ahi + aoff0 + k0, ah_d0);
    gld_lds16(Ahi + aoff1 + k0, ah_d1);
    gld_lds16(Alo + aoff0 + k0, al_d0);
    gld_lds16(Alo + aoff1 + k0, al_d1);
    gld_lds16(Whi + woff0 + k0, wh_d0);
    gld_lds16(Whi + woff1 + k0, wh_d1);
    gld_lds16(Wlo + woff0 + k0, wl_d0);
    gld_lds16(Wlo + woff1 + k0, wl_d1);
    __syncthreads();  // stage complete (barrier drains vmcnt)

    short8 ah[4], al[4], wh[4], wl[4];
#pragma unroll
    for (int mi = 0; mi < 4; ++mi) {
      int ro = (wm * 64 + mi * 16 + l15) * 32 + kg * 8;
      ah[mi] = *(const short8*)&AH[ro];
      al[mi] = *(const short8*)&AL[ro];
    }
#pragma unroll
    for (int ni = 0; ni < 4; ++ni) {
      int ro = (wn * 64 + ni * 16 + l15) * 32 + kg * 8;
      wh[ni] = *(const short8*)&WH[ro];
      wl[ni] = *(const short8*)&WL[ro];
    }

#pragma unroll
    for (int mi = 0; mi < 4; ++mi)
#pragma unroll
      for (int ni = 0; ni < 4; ++ni) {
        acc[mi][ni] = __builtin_amdgcn_mfma_f32_16x16x32_bf16(
            ah[mi], wh[ni], acc[mi][ni], 0, 0, 0);
        acc[mi][ni] = __builtin_amdgcn_mfma_f32_16x16x32_bf16(
            ah[mi], wl[ni], acc[mi][ni], 0, 0, 0);
        acc[mi][ni] = __builtin_amdgcn_mfma_f32_16x16x32_bf16(
            al[mi], wh[ni], acc[mi][ni], 0, 0, 0);
      }
  }

  // C/D layout (m89-verified): col = lane&15, row = (lane>>4)*4 + reg
#pragma unroll
  for (int mi = 0; mi < 4; ++mi)
#pragma unroll
    for (int ni = 0; ni < 4; ++ni)
#pragma unroll
      for (int r = 0; r < 4; ++r) {
        int grow = bx * 128 + wm * 64 + mi * 16 + kg * 4 + r;
        int gcol = by * 128 + wn * 64 + ni * 16 + l15;
        G[(size_t)grow * 4096 + gcol] = acc[mi][ni][r];
      }
}

// ---------------- Recurrence: persistent, one block per (b,h) ----------------
static __device__ __forceinline__ float dot4(float4 a, float4 b, float acc) {
  acc = fmaf(a.x, b.x, acc);
  acc = fmaf(a.y, b.y, acc);
  acc = fmaf(a.z, b.z, acc);
  acc = fmaf(a.w, b.w, acc);
  return acc;
}

__global__ __launch_bounds__(256, 1)
void recur_kernel(const float* __restrict__ G,     // [32*tch, 4096] chunk
                  const float* __restrict__ Whh,   // [8,512,128]
                  const float* __restrict__ bias,  // [8,512]
                  float* __restrict__ out,         // [32,512,1024]
                  float* __restrict__ state,       // 4 x [32,8,128]
                  int t0, int tch, int first) {
  int blk = blockIdx.x;
  int b = blk >> 3, h = blk & 7;
  int t = threadIdx.x;

  __shared__ __align__(16) float h_s[128];
  __shared__ __align__(16) float lin_s[512];

  const float4* w0p = (const float4*)(Whh + (size_t)(h * 512 + 2 * t) * 128);
  const float4* w1p = w0p + 32;
  float4 w0[32], w1[32];
#pragma unroll
  for (int j = 0; j < 32; ++j) w0[j] = w0p[j];
#pragma unroll
  for (int j = 0; j < 32; ++j) w1[j] = w1p[j];

  float b0 = bias[h * 512 + 2 * t];
  float b1 = bias[h * 512 + 2 * t + 1];

  float c_r = 0.f, n_r = 0.f, m_r = 0.f;
  int si = (b * 8 + h) * 128 + (t & 127);
  if (t < 128) {
    float h0 = 0.f;
    if (!first) {
      h0 = state[si];
      c_r = state[32768 + si];
      m_r = state[65536 + si];
      n_r = state[98304 + si];
    }
    h_s[t] = h0;
  }
  __syncthreads();

  const float* gp = G + (size_t)(b * tch) * 4096 + h * 512 + 2 * t;
  float* op = out + ((size_t)b * 512 + t0) * 1024 + h * 128 + (t & 127);

  for (int s = 0; s < tch; ++s) {
    float2 g = *(const float2*)gp;  // issued early, consumed after matvec
    gp += 4096;

    float a0 = 0.f, a1 = 0.f, a2 = 0.f, a3 = 0.f;
#pragma unroll
    for (int j = 0; j < 32; j += 2) {
      float4 hv0 = ((const float4*)h_s)[j];
      float4 hv1 = ((const float4*)h_s)[j + 1];
      a0 = dot4(w0[j], hv0, a0);
      a1 = dot4(w1[j], hv0, a1);
      a2 = dot4(w0[j + 1], hv1, a2);
      a3 = dot4(w1[j + 1], hv1, a3);
    }
    lin_s[2 * t]     = b0 + g.x + a0 + a2;
    lin_s[2 * t + 1] = b1 + g.y + a1 + a3;
    __syncthreads();

    if (t < 128) {
      float iv = lin_s[t];
      float fv = lin_s[128 + t];
      float zv = lin_s[256 + t];
      float ov = lin_s[384 + t];
      float e2z = __expf(2.f * zv);
      float zt = 1.f - 2.f / (e2z + 1.f);          // tanh, inf-safe
      float og = 1.f / (1.f + __expf(-ov));        // sigmoid
      float mn = fmaxf(fv + m_r, iv);
      float ie = __expf(iv - mn);
      float fe = __expf(fv + m_r - mn);
      c_r = fe * c_r + ie * zt;
      n_r = fe * n_r + ie;
      m_r = mn;
      float hnew = og * (c_r / n_r);
      h_s[t] = hnew;
      op[(size_t)s * 1024] = hnew;
    }
    __syncthreads();
  }

  if (t < 128) {
    state[si] = h_s[t];
    state[32768 + si] = c_r;
    state[65536 + si] = m_r;
    state[98304 + si] = n_r;
  }
}

// ---------------- launch ----------------
extern "C" void kernel_launch(void* const* d_in, const int* in_sizes, int n_in,
                              void* d_out, int out_size, void* d_ws, size_t ws_size,
                              hipStream_t stream) {
  const float* xs   = (const float*)d_in[0];
  const float* wif  = (const float*)d_in[1];
  const float* wzo  = (const float*)d_in[2];
  const float* whh  = (const float*)d_in[3];
  const float* bias = (const float*)d_in[4];
  float* out = (float*)d_out;

  char* ws = (char*)d_ws;
  unsigned short* Ahi = (unsigned short*)ws;                 // 33,554,432 B
  unsigned short* Alo = (unsigned short*)(ws + 33554432);    // 33,554,432 B
  unsigned short* Whi = (unsigned short*)(ws + 67108864);    //  8,388,608 B
  unsigned short* Wlo = (unsigned short*)(ws + 75497472);    //  8,388,608 B
  const size_t gbase = 83886080;

  // adaptive time chunk so G fits in ws
  int tch = 128;
  while (tch > 8 &&
         gbase + (size_t)32 * tch * 4096 * 4 + 524288 > ws_size)
    tch >>= 1;
  int ltch = (tch == 128) ? 7 : (tch == 64) ? 6 : (tch == 32) ? 5
             : (tch == 16) ? 4 : 3;

  float* G = (float*)(ws + gbase);
  float* state = (float*)(ws + gbase + (size_t)32 * tch * 4096 * 4);

  conv_x_split<<<16384, 256, 0, stream>>>(xs, Ahi, Alo, 4194304);
  conv_w_split<<<4096, 256, 0, stream>>>(wif, wzo, Whi, Wlo);

  for (int t0 = 0; t0 < 512; t0 += tch) {
    gemm3_kernel<<<dim3(tch / 4, 32), 256, 0, stream>>>(Ahi, Alo, Whi, Wlo,
                                                        G, t0, ltch);
    recur_kernel<<<256, 256, 0, stream>>>(G, whh, bias, out, state, t0, tch,
                                          t0 == 0);
  }
}

// Round 3
// 1153.244 us; speedup vs baseline: 1.2705x; 1.2705x over previous
//
#include <hip/hip_runtime.h>
#include <hip/hip_bf16.h>
#include <stdint.h>

// Problem dims
#define B_SZ 32
#define T_SZ 512
#define I_SZ 1024
#define H_SZ 8
#define HS_SZ 128

typedef __attribute__((ext_vector_type(8))) short short8;
typedef __attribute__((ext_vector_type(4))) float f32x4;

// ---------------- fp32 <-> bf16 helpers ----------------
static __device__ __forceinline__ unsigned short f2bf(float f) {
  union { float f; unsigned int u; } c; c.f = f;
  unsigned int u = c.u;
  unsigned int r = (u + 0x7fffu + ((u >> 16) & 1u)) >> 16;
  return (unsigned short)r;
}
static __device__ __forceinline__ float bf2f(unsigned short s) {
  union { unsigned int u; float f; } c; c.u = ((unsigned int)s) << 16;
  return c.f;
}
// split x into hi (bf16) + lo (bf16 of residual)
static __device__ __forceinline__ void split2(float x, unsigned short& hi,
                                              unsigned short& lo) {
  hi = f2bf(x);
  lo = f2bf(x - bf2f(hi));
}

__global__ void conv_x_split(const float* __restrict__ x,
                             unsigned short* __restrict__ ohi,
                             unsigned short* __restrict__ olo, int n4) {
  int i = blockIdx.x * blockDim.x + threadIdx.x;
  if (i >= n4) return;
  float4 v = ((const float4*)x)[i];
  ushort4 h, l;
  split2(v.x, h.x, l.x);
  split2(v.y, h.y, l.y);
  split2(v.z, h.z, l.z);
  split2(v.w, h.w, l.w);
  ((ushort4*)ohi)[i] = h;
  ((ushort4*)olo)[i] = l;
}

// Combined weight Wc[4096][1024], row n = h*512 + k4:
//   k4 in [0,256)   -> weight_if[h][k4][:]      (i rows then f rows)
//   k4 in [256,512) -> weight_zo[h][k4-256][:]  (z rows then o rows)
__global__ void conv_w_split(const float* __restrict__ wif,
                             const float* __restrict__ wzo,
                             unsigned short* __restrict__ ohi,
                             unsigned short* __restrict__ olo) {
  int i = blockIdx.x * blockDim.x + threadIdx.x;  // float4 index
  int flat = i * 4;
  int n = flat >> 10;
  int col = flat & 1023;
  int h = n >> 9, k4 = n & 511;
  const float* src = (k4 < 256)
                         ? (wif + ((size_t)(h * 256 + k4) * 1024 + col))
                         : (wzo + ((size_t)(h * 256 + (k4 - 256)) * 1024 + col));
  float4 v = *(const float4*)src;
  ushort4 hh, ll;
  split2(v.x, hh.x, ll.x);
  split2(v.y, hh.y, ll.y);
  split2(v.z, hh.z, ll.z);
  split2(v.w, hh.w, ll.w);
  ((ushort4*)ohi)[i] = hh;
  ((ushort4*)olo)[i] = ll;
}

// ---------------- GEMM (3-pass split bf16 = emulated fp32) ----------------
// G[32*tch x 4096] = A_chunk[32*tch x 1024] * Wc^T, acc += AhWh + AhWl + AlWh.
// 128x128 tile, BK=32, 4 waves (2x2), 4x4 16x16x32 frags per wave,
// global_load_lds width=16 staging, 2 barriers per K-step.
__device__ __forceinline__ void gld_lds16(const void* g, void* l) {
  __builtin_amdgcn_global_load_lds(
      (const __attribute__((address_space(1))) void*)g,
      (__attribute__((address_space(3))) void*)l, 16, 0, 0);
}

__global__ __launch_bounds__(256)
void gemm3_kernel(const unsigned short* __restrict__ Ahi,
                  const unsigned short* __restrict__ Alo,
                  const unsigned short* __restrict__ Whi,
                  const unsigned short* __restrict__ Wlo,
                  float* __restrict__ G, int t0, int ltch) {
  __shared__ short AH[128 * 32];
  __shared__ short AL[128 * 32];
  __shared__ short WH[128 * 32];
  __shared__ short WL[128 * 32];

  int tid = threadIdx.x;
  int lane = tid & 63, wave = tid >> 6;
  int wm = wave >> 1, wn = wave & 1;
  int bx = blockIdx.x, by = blockIdx.y;
  int l15 = lane & 15, kg = lane >> 4;
  int tchm = (1 << ltch) - 1;

  f32x4 zero4 = {0.f, 0.f, 0.f, 0.f};
  f32x4 acc[4][4];
#pragma unroll
  for (int mi = 0; mi < 4; ++mi)
#pragma unroll
    for (int ni = 0; ni < 4; ++ni) acc[mi][ni] = zero4;

  // staging unit u in [0,512), 16B each; lds short offset = u*8
  int u0 = wave * 128 + lane;
  int u1 = u0 + 64;
  // chunk row r -> global xs row: b = r>>ltch, m = r&tchm, row = b*512+t0+m
  int r0 = bx * 128 + (u0 >> 2);
  int r1 = bx * 128 + (u1 >> 2);
  size_t arow0 = (size_t)(r0 >> ltch) * 512 + t0 + (r0 & tchm);
  size_t arow1 = (size_t)(r1 >> ltch) * 512 + t0 + (r1 & tchm);
  size_t aoff0 = arow0 * 1024 + (u0 & 3) * 8;
  size_t aoff1 = arow1 * 1024 + (u1 & 3) * 8;
  size_t woff0 = (size_t)(by * 128 + (u0 >> 2)) * 1024 + (u0 & 3) * 8;
  size_t woff1 = (size_t)(by * 128 + (u1 >> 2)) * 1024 + (u1 & 3) * 8;

  short* ah_d0 = &AH[wave * 1024];
  short* ah_d1 = &AH[wave * 1024 + 512];
  short* al_d0 = &AL[wave * 1024];
  short* al_d1 = &AL[wave * 1024 + 512];
  short* wh_d0 = &WH[wave * 1024];
  short* wh_d1 = &WH[wave * 1024 + 512];
  short* wl_d0 = &WL[wave * 1024];
  short* wl_d1 = &WL[wave * 1024 + 512];

  for (int k0 = 0; k0 < 1024; k0 += 32) {
    __syncthreads();  // previous compute done before overwrite
    gld_lds16(Ahi + aoff0 + k0, ah_d0);
    gld_lds16(Ahi + aoff1 + k0, ah_d1);
    gld_lds16(Alo + aoff0 + k0, al_d0);
    gld_lds16(Alo + aoff1 + k0, al_d1);
    gld_lds16(Whi + woff0 + k0, wh_d0);
    gld_lds16(Whi + woff1 + k0, wh_d1);
    gld_lds16(Wlo + woff0 + k0, wl_d0);
    gld_lds16(Wlo + woff1 + k0, wl_d1);
    __syncthreads();  // stage complete (barrier drains vmcnt)

    short8 ah[4], al[4], wh[4], wl[4];
#pragma unroll
    for (int mi = 0; mi < 4; ++mi) {
      int ro = (wm * 64 + mi * 16 + l15) * 32 + kg * 8;
      ah[mi] = *(const short8*)&AH[ro];
      al[mi] = *(const short8*)&AL[ro];
    }
#pragma unroll
    for (int ni = 0; ni < 4; ++ni) {
      int ro = (wn * 64 + ni * 16 + l15) * 32 + kg * 8;
      wh[ni] = *(const short8*)&WH[ro];
      wl[ni] = *(const short8*)&WL[ro];
    }

#pragma unroll
    for (int mi = 0; mi < 4; ++mi)
#pragma unroll
      for (int ni = 0; ni < 4; ++ni) {
        acc[mi][ni] = __builtin_amdgcn_mfma_f32_16x16x32_bf16(
            ah[mi], wh[ni], acc[mi][ni], 0, 0, 0);
        acc[mi][ni] = __builtin_amdgcn_mfma_f32_16x16x32_bf16(
            ah[mi], wl[ni], acc[mi][ni], 0, 0, 0);
        acc[mi][ni] = __builtin_amdgcn_mfma_f32_16x16x32_bf16(
            al[mi], wh[ni], acc[mi][ni], 0, 0, 0);
      }
  }

  // C/D layout (m89-verified): col = lane&15, row = (lane>>4)*4 + reg
#pragma unroll
  for (int mi = 0; mi < 4; ++mi)
#pragma unroll
    for (int ni = 0; ni < 4; ++ni)
#pragma unroll
      for (int r = 0; r < 4; ++r) {
        int grow = bx * 128 + wm * 64 + mi * 16 + kg * 4 + r;
        int gcol = by * 128 + wn * 64 + ni * 16 + l15;
        G[(size_t)grow * 4096 + gcol] = acc[mi][ni][r];
      }
}

// ---------------- Recurrence: persistent, one block per (b,h) ----------------
// 256 blocks x 512 threads (8 waves = 2/SIMD). Thread j owns W_hh row j of
// head h in 128 VGPRs (fp32). h broadcast via LDS (uniform-address b128
// reads). Activation applied wave-uniformly in the matvec threads:
//   rows   0..255 (waves 0-3): raw i/f
//   rows 256..383 (waves 4-5): tanh(z)
//   rows 384..511 (waves 6-7): sigmoid(o)
// Serial gate section (threads 0..127) is just the stabilizer chain.
// G prefetched one full step ahead into a register.
static __device__ __forceinline__ float dot4(float4 a, float4 b, float acc) {
  acc = fmaf(a.x, b.x, acc);
  acc = fmaf(a.y, b.y, acc);
  acc = fmaf(a.z, b.z, acc);
  acc = fmaf(a.w, b.w, acc);
  return acc;
}

__global__ __launch_bounds__(512, 2)
void recur_kernel(const float* __restrict__ G,     // [32*tch, 4096] chunk
                  const float* __restrict__ Whh,   // [8,512,128]
                  const float* __restrict__ bias,  // [8,512]
                  float* __restrict__ out,         // [32,512,1024]
                  float* __restrict__ state,       // 4 x [32,8,128]
                  int t0, int tch, int first) {
  int blk = blockIdx.x;
  int b = blk >> 3, h = blk & 7;
  int j = threadIdx.x;  // row 0..511

  __shared__ __align__(16) float h_s[128];
  __shared__ __align__(16) float lin_s[512];

  // own W_hh row in registers (32 float4 = 128 VGPR)
  const float4* wp = (const float4*)(Whh + ((size_t)h * 512 + j) * 128);
  float4 w[32];
#pragma unroll
  for (int q = 0; q < 32; ++q) w[q] = wp[q];
  float bj = bias[h * 512 + j];

  float c_r = 0.f, n_r = 0.f, m_r = 0.f;
  int e = j & 127;
  int si = (b * 8 + h) * 128 + e;
  if (j < 128) {
    float h0 = 0.f;
    if (!first) {
      h0 = state[si];
      c_r = state[32768 + si];
      m_r = state[65536 + si];
      n_r = state[98304 + si];
    }
    h_s[j] = h0;
  }
  __syncthreads();

  const float* gp = G + (size_t)(b * tch) * 4096 + h * 512 + j;
  float* op = out + ((size_t)b * 512 + t0) * 1024 + h * 128 + e;

  float g_cur = *gp;  // step-0 preactivation contribution
  for (int s = 0; s < tch; ++s) {
    // prefetch next step's G (consumed next iteration -> full step of slack)
    float g_next = 0.f;
    if (s + 1 < tch) g_next = gp[(size_t)(s + 1) * 4096];

    float a0 = 0.f, a1 = 0.f, a2 = 0.f, a3 = 0.f;
    const float4* hv = (const float4*)h_s;
#pragma unroll
    for (int q = 0; q < 32; q += 4) {
      a0 = dot4(w[q],     hv[q],     a0);
      a1 = dot4(w[q + 1], hv[q + 1], a1);
      a2 = dot4(w[q + 2], hv[q + 2], a2);
      a3 = dot4(w[q + 3], hv[q + 3], a3);
    }
    float val = bj + g_cur + ((a0 + a1) + (a2 + a3));
    g_cur = g_next;

    // wave-uniform activation
    if (j >= 384) {                      // o -> sigmoid
      val = 1.f / (1.f + __expf(-val));
    } else if (j >= 256) {               // z -> tanh (inf-safe)
      float e2 = __expf(2.f * val);
      val = 1.f - 2.f / (e2 + 1.f);
    }
    lin_s[j] = val;
    __syncthreads();

    if (j < 128) {
      float iv = lin_s[j];
      float fv = lin_s[128 + j];
      float zt = lin_s[256 + j];
      float og = lin_s[384 + j];
      float mn = fmaxf(fv + m_r, iv);
      float ie = __expf(iv - mn);
      float fe = __expf(fv + m_r - mn);
      c_r = fe * c_r + ie * zt;
      n_r = fe * n_r + ie;
      m_r = mn;
      float hnew = og * (c_r / n_r);
      h_s[j] = hnew;
      op[(size_t)s * 1024] = hnew;
    }
    __syncthreads();
  }

  if (j < 128) {
    state[si] = h_s[j];
    state[32768 + si] = c_r;
    state[65536 + si] = m_r;
    state[98304 + si] = n_r;
  }
}

// ---------------- launch ----------------
extern "C" void kernel_launch(void* const* d_in, const int* in_sizes, int n_in,
                              void* d_out, int out_size, void* d_ws, size_t ws_size,
                              hipStream_t stream) {
  const float* xs   = (const float*)d_in[0];
  const float* wif  = (const float*)d_in[1];
  const float* wzo  = (const float*)d_in[2];
  const float* whh  = (const float*)d_in[3];
  const float* bias = (const float*)d_in[4];
  float* out = (float*)d_out;

  char* ws = (char*)d_ws;
  unsigned short* Ahi = (unsigned short*)ws;                 // 33,554,432 B
  unsigned short* Alo = (unsigned short*)(ws + 33554432);    // 33,554,432 B
  unsigned short* Whi = (unsigned short*)(ws + 67108864);    //  8,388,608 B
  unsigned short* Wlo = (unsigned short*)(ws + 75497472);    //  8,388,608 B
  const size_t gbase = 83886080;

  // adaptive time chunk so G fits in ws
  int tch = 128;
  while (tch > 8 &&
         gbase + (size_t)32 * tch * 4096 * 4 + 524288 > ws_size)
    tch >>= 1;
  int ltch = (tch == 128) ? 7 : (tch == 64) ? 6 : (tch == 32) ? 5
             : (tch == 16) ? 4 : 3;

  float* G = (float*)(ws + gbase);
  float* state = (float*)(ws + gbase + (size_t)32 * tch * 4096 * 4);

  conv_x_split<<<16384, 256, 0, stream>>>(xs, Ahi, Alo, 4194304);
  conv_w_split<<<4096, 256, 0, stream>>>(wif, wzo, Whi, Wlo);

  for (int t0 = 0; t0 < 512; t0 += tch) {
    gemm3_kernel<<<dim3(tch / 4, 32), 256, 0, stream>>>(Ahi, Alo, Whi, Wlo,
                                                        G, t0, ltch);
    recur_kernel<<<256, 512, 0, stream>>>(G, whh, bias, out, state, t0, tch,
                                          t0 == 0);
  }
}

// Round 4
// 1136.086 us; speedup vs baseline: 1.2896x; 1.0151x over previous
//
#include <hip/hip_runtime.h>
#include <hip/hip_bf16.h>
#include <stdint.h>

// Problem dims
#define B_SZ 32
#define T_SZ 512
#define I_SZ 1024
#define H_SZ 8
#define HS_SZ 128

typedef __attribute__((ext_vector_type(8))) short short8;
typedef __attribute__((ext_vector_type(4))) float f32x4;

// ---------------- fp32 <-> bf16 helpers ----------------
static __device__ __forceinline__ unsigned short f2bf(float f) {
  union { float f; unsigned int u; } c; c.f = f;
  unsigned int u = c.u;
  unsigned int r = (u + 0x7fffu + ((u >> 16) & 1u)) >> 16;
  return (unsigned short)r;
}
static __device__ __forceinline__ float bf2f(unsigned short s) {
  union { unsigned int u; float f; } c; c.u = ((unsigned int)s) << 16;
  return c.f;
}
// split x into hi (bf16) + lo (bf16 of residual)
static __device__ __forceinline__ void split2(float x, unsigned short& hi,
                                              unsigned short& lo) {
  hi = f2bf(x);
  lo = f2bf(x - bf2f(hi));
}

__global__ void conv_x_split(const float* __restrict__ x,
                             unsigned short* __restrict__ ohi,
                             unsigned short* __restrict__ olo, int n4) {
  int i = blockIdx.x * blockDim.x + threadIdx.x;
  if (i >= n4) return;
  float4 v = ((const float4*)x)[i];
  ushort4 h, l;
  split2(v.x, h.x, l.x);
  split2(v.y, h.y, l.y);
  split2(v.z, h.z, l.z);
  split2(v.w, h.w, l.w);
  ((ushort4*)ohi)[i] = h;
  ((ushort4*)olo)[i] = l;
}

// Combined weight Wc[4096][1024], row n = h*512 + k4:
//   k4 in [0,256)   -> weight_if[h][k4][:]      (i rows then f rows)
//   k4 in [256,512) -> weight_zo[h][k4-256][:]  (z rows then o rows)
__global__ void conv_w_split(const float* __restrict__ wif,
                             const float* __restrict__ wzo,
                             unsigned short* __restrict__ ohi,
                             unsigned short* __restrict__ olo) {
  int i = blockIdx.x * blockDim.x + threadIdx.x;  // float4 index
  int flat = i * 4;
  int n = flat >> 10;
  int col = flat & 1023;
  int h = n >> 9, k4 = n & 511;
  const float* src = (k4 < 256)
                         ? (wif + ((size_t)(h * 256 + k4) * 1024 + col))
                         : (wzo + ((size_t)(h * 256 + (k4 - 256)) * 1024 + col));
  float4 v = *(const float4*)src;
  ushort4 hh, ll;
  split2(v.x, hh.x, ll.x);
  split2(v.y, hh.y, ll.y);
  split2(v.z, hh.z, ll.z);
  split2(v.w, hh.w, ll.w);
  ((ushort4*)ohi)[i] = hh;
  ((ushort4*)olo)[i] = ll;
}

// ---------------- GEMM (3-pass split bf16 = emulated fp32) ----------------
// G[32*tch x 4096] = A_chunk[32*tch x 1024] * Wc^T, acc += AhWh + AhWl + AlWh.
__device__ __forceinline__ void gld_lds16(const void* g, void* l) {
  __builtin_amdgcn_global_load_lds(
      (const __attribute__((address_space(1))) void*)g,
      (__attribute__((address_space(3))) void*)l, 16, 0, 0);
}

__global__ __launch_bounds__(256)
void gemm3_kernel(const unsigned short* __restrict__ Ahi,
                  const unsigned short* __restrict__ Alo,
                  const unsigned short* __restrict__ Whi,
                  const unsigned short* __restrict__ Wlo,
                  float* __restrict__ G, int t0, int ltch) {
  __shared__ short AH[128 * 32];
  __shared__ short AL[128 * 32];
  __shared__ short WH[128 * 32];
  __shared__ short WL[128 * 32];

  int tid = threadIdx.x;
  int lane = tid & 63, wave = tid >> 6;
  int wm = wave >> 1, wn = wave & 1;
  int bx = blockIdx.x, by = blockIdx.y;
  int l15 = lane & 15, kg = lane >> 4;
  int tchm = (1 << ltch) - 1;

  f32x4 zero4 = {0.f, 0.f, 0.f, 0.f};
  f32x4 acc[4][4];
#pragma unroll
  for (int mi = 0; mi < 4; ++mi)
#pragma unroll
    for (int ni = 0; ni < 4; ++ni) acc[mi][ni] = zero4;

  int u0 = wave * 128 + lane;
  int u1 = u0 + 64;
  int r0 = bx * 128 + (u0 >> 2);
  int r1 = bx * 128 + (u1 >> 2);
  size_t arow0 = (size_t)(r0 >> ltch) * 512 + t0 + (r0 & tchm);
  size_t arow1 = (size_t)(r1 >> ltch) * 512 + t0 + (r1 & tchm);
  size_t aoff0 = arow0 * 1024 + (u0 & 3) * 8;
  size_t aoff1 = arow1 * 1024 + (u1 & 3) * 8;
  size_t woff0 = (size_t)(by * 128 + (u0 >> 2)) * 1024 + (u0 & 3) * 8;
  size_t woff1 = (size_t)(by * 128 + (u1 >> 2)) * 1024 + (u1 & 3) * 8;

  short* ah_d0 = &AH[wave * 1024];
  short* ah_d1 = &AH[wave * 1024 + 512];
  short* al_d0 = &AL[wave * 1024];
  short* al_d1 = &AL[wave * 1024 + 512];
  short* wh_d0 = &WH[wave * 1024];
  short* wh_d1 = &WH[wave * 1024 + 512];
  short* wl_d0 = &WL[wave * 1024];
  short* wl_d1 = &WL[wave * 1024 + 512];

  for (int k0 = 0; k0 < 1024; k0 += 32) {
    __syncthreads();
    gld_lds16(Ahi + aoff0 + k0, ah_d0);
    gld_lds16(Ahi + aoff1 + k0, ah_d1);
    gld_lds16(Alo + aoff0 + k0, al_d0);
    gld_lds16(Alo + aoff1 + k0, al_d1);
    gld_lds16(Whi + woff0 + k0, wh_d0);
    gld_lds16(Whi + woff1 + k0, wh_d1);
    gld_lds16(Wlo + woff0 + k0, wl_d0);
    gld_lds16(Wlo + woff1 + k0, wl_d1);
    __syncthreads();

    short8 ah[4], al[4], wh[4], wl[4];
#pragma unroll
    for (int mi = 0; mi < 4; ++mi) {
      int ro = (wm * 64 + mi * 16 + l15) * 32 + kg * 8;
      ah[mi] = *(const short8*)&AH[ro];
      al[mi] = *(const short8*)&AL[ro];
    }
#pragma unroll
    for (int ni = 0; ni < 4; ++ni) {
      int ro = (wn * 64 + ni * 16 + l15) * 32 + kg * 8;
      wh[ni] = *(const short8*)&WH[ro];
      wl[ni] = *(const short8*)&WL[ro];
    }

#pragma unroll
    for (int mi = 0; mi < 4; ++mi)
#pragma unroll
      for (int ni = 0; ni < 4; ++ni) {
        acc[mi][ni] = __builtin_amdgcn_mfma_f32_16x16x32_bf16(
            ah[mi], wh[ni], acc[mi][ni], 0, 0, 0);
        acc[mi][ni] = __builtin_amdgcn_mfma_f32_16x16x32_bf16(
            ah[mi], wl[ni], acc[mi][ni], 0, 0, 0);
        acc[mi][ni] = __builtin_amdgcn_mfma_f32_16x16x32_bf16(
            al[mi], wh[ni], acc[mi][ni], 0, 0, 0);
      }
  }

  // C/D layout (m89-verified): col = lane&15, row = (lane>>4)*4 + reg
#pragma unroll
  for (int mi = 0; mi < 4; ++mi)
#pragma unroll
    for (int ni = 0; ni < 4; ++ni)
#pragma unroll
      for (int r = 0; r < 4; ++r) {
        int grow = bx * 128 + wm * 64 + mi * 16 + kg * 4 + r;
        int gcol = by * 128 + wn * 64 + ni * 16 + l15;
        G[(size_t)grow * 4096 + gcol] = acc[mi][ni][r];
      }
}

// ---------------- Recurrence ----------------
// 256 blocks (one per (b,h)) x 512 threads (8 waves = 2/SIMD).
// Thread t = p*128 + e  (p = col-slice 0..3, e = element 0..127) owns the
// 32-column slice [32p, 32p+32) of W_hh rows {e, 128+e, 256+e, 384+e}
// (i/f/z/o rows for element e) as 128 fp32 VGPRs, pinned via asm so the
// compiler cannot rematerialize the loads inside the step loop (round-3
// post-mortem: VGPR=80 proved rematerialization; step was LDS-broadcast
// bound at 256 KB/CU/step). Now each thread reads only its 128 B h-slice:
// 64 KB/CU/step. Partials reduced via LDS [gate][p][e] (conflict-free).
static __device__ __forceinline__ float dot4(float4 a, float4 b, float acc) {
  acc = fmaf(a.x, b.x, acc);
  acc = fmaf(a.y, b.y, acc);
  acc = fmaf(a.z, b.z, acc);
  acc = fmaf(a.w, b.w, acc);
  return acc;
}

__global__ __launch_bounds__(512, 2)
void recur_kernel(const float* __restrict__ G,     // [32*tch, 4096] chunk
                  const float* __restrict__ Whh,   // [8,512,128]
                  const float* __restrict__ bias,  // [8,512]
                  float* __restrict__ out,         // [32,512,1024]
                  float* __restrict__ state,       // 4 x [32,8,128]
                  int t0, int tch, int first) {
  int blk = blockIdx.x;
  int b = blk >> 3, h = blk & 7;
  int t = threadIdx.x;
  int e = t & 127;  // element
  int p = t >> 7;   // col-slice

  __shared__ __align__(16) float hbuf[2][128];
  __shared__ float part_s[4][4][128];  // [gate][p][e]

  // own W slice: rows g*128+e, cols [32p,32p+32)  -> 4x8 float4 = 128 VGPR
  float4 w[4][8];
  const float* wbase = Whh + (size_t)h * 65536 + (size_t)p * 32;
#pragma unroll
  for (int g = 0; g < 4; ++g) {
    const float4* wp = (const float4*)(wbase + (size_t)(g * 128 + e) * 128);
#pragma unroll
    for (int q = 0; q < 8; ++q) {
      w[g][q] = wp[q];
      // pin: value becomes asm-defined -> cannot be rematerialized
      asm volatile("" : "+v"(w[g][q].x), "+v"(w[g][q].y),
                        "+v"(w[g][q].z), "+v"(w[g][q].w));
    }
  }

  float c_r = 0.f, n_r = 0.f, m_r = 0.f;
  int si = (b * 8 + h) * 128 + e;
  float bj0 = 0.f, bj1 = 0.f, bj2 = 0.f, bj3 = 0.f;
  float gc0 = 0.f, gc1 = 0.f, gc2 = 0.f, gc3 = 0.f;
  const float* gpb = G + (size_t)(b * tch) * 4096 + h * 512 + e;
  float* op = out + ((size_t)b * 512 + t0) * 1024 + h * 128 + e;

  if (t < 128) {
    float h0 = 0.f;
    if (!first) {
      h0 = state[si];
      c_r = state[32768 + si];
      m_r = state[65536 + si];
      n_r = state[98304 + si];
    }
    hbuf[0][e] = h0;
    bj0 = bias[h * 512 + e];
    bj1 = bias[h * 512 + 128 + e];
    bj2 = bias[h * 512 + 256 + e];
    bj3 = bias[h * 512 + 384 + e];
    gc0 = gpb[0];
    gc1 = gpb[128];
    gc2 = gpb[256];
    gc3 = gpb[384];
  }
  __syncthreads();

  int cur = 0;
  for (int s = 0; s < tch; ++s) {
    // ---- matvec phase (all 512 threads) ----
    const float4* hv = (const float4*)&hbuf[cur][p * 32];
    float a0 = 0.f, a1 = 0.f, a2 = 0.f, a3 = 0.f;
#pragma unroll
    for (int q = 0; q < 8; ++q) {
      float4 h4 = hv[q];
      a0 = dot4(w[0][q], h4, a0);
      a1 = dot4(w[1][q], h4, a1);
      a2 = dot4(w[2][q], h4, a2);
      a3 = dot4(w[3][q], h4, a3);
    }
    part_s[0][p][e] = a0;
    part_s[1][p][e] = a1;
    part_s[2][p][e] = a2;
    part_s[3][p][e] = a3;
    __syncthreads();

    // ---- gate phase (threads 0..127) ----
    if (t < 128) {
      // prefetch next step's G early (consumed at end of this phase)
      float gn0 = 0.f, gn1 = 0.f, gn2 = 0.f, gn3 = 0.f;
      if (s + 1 < tch) {
        const float* gnp = gpb + (size_t)(s + 1) * 4096;
        gn0 = gnp[0];
        gn1 = gnp[128];
        gn2 = gnp[256];
        gn3 = gnp[384];
      }
      float iv = bj0 + gc0 + ((part_s[0][0][e] + part_s[0][1][e]) +
                              (part_s[0][2][e] + part_s[0][3][e]));
      float fv = bj1 + gc1 + ((part_s[1][0][e] + part_s[1][1][e]) +
                              (part_s[1][2][e] + part_s[1][3][e]));
      float zv = bj2 + gc2 + ((part_s[2][0][e] + part_s[2][1][e]) +
                              (part_s[2][2][e] + part_s[2][3][e]));
      float ov = bj3 + gc3 + ((part_s[3][0][e] + part_s[3][1][e]) +
                              (part_s[3][2][e] + part_s[3][3][e]));
      float e2 = __expf(2.f * zv);
      float zt = 1.f - 2.f / (e2 + 1.f);       // tanh, inf-safe
      float og = 1.f / (1.f + __expf(-ov));    // sigmoid
      float mn = fmaxf(fv + m_r, iv);
      float ie = __expf(iv - mn);
      float fe = __expf(fv + m_r - mn);
      c_r = fe * c_r + ie * zt;
      n_r = fe * n_r + ie;
      m_r = mn;
      float hnew = og * (c_r / n_r);
      hbuf[cur ^ 1][e] = hnew;
      op[(size_t)s * 1024] = hnew;
      gc0 = gn0; gc1 = gn1; gc2 = gn2; gc3 = gn3;
    }
    __syncthreads();
    cur ^= 1;
  }

  if (t < 128) {
    state[si] = hbuf[cur][e];
    state[32768 + si] = c_r;
    state[65536 + si] = m_r;
    state[98304 + si] = n_r;
  }
}

// ---------------- launch ----------------
extern "C" void kernel_launch(void* const* d_in, const int* in_sizes, int n_in,
                              void* d_out, int out_size, void* d_ws, size_t ws_size,
                              hipStream_t stream) {
  const float* xs   = (const float*)d_in[0];
  const float* wif  = (const float*)d_in[1];
  const float* wzo  = (const float*)d_in[2];
  const float* whh  = (const float*)d_in[3];
  const float* bias = (const float*)d_in[4];
  float* out = (float*)d_out;

  char* ws = (char*)d_ws;
  unsigned short* Ahi = (unsigned short*)ws;                 // 33,554,432 B
  unsigned short* Alo = (unsigned short*)(ws + 33554432);    // 33,554,432 B
  unsigned short* Whi = (unsigned short*)(ws + 67108864);    //  8,388,608 B
  unsigned short* Wlo = (unsigned short*)(ws + 75497472);    //  8,388,608 B
  const size_t gbase = 83886080;

  // adaptive time chunk so G fits in ws
  int tch = 128;
  while (tch > 8 &&
         gbase + (size_t)32 * tch * 4096 * 4 + 524288 > ws_size)
    tch >>= 1;
  int ltch = (tch == 128) ? 7 : (tch == 64) ? 6 : (tch == 32) ? 5
             : (tch == 16) ? 4 : 3;

  float* G = (float*)(ws + gbase);
  float* state = (float*)(ws + gbase + (size_t)32 * tch * 4096 * 4);

  conv_x_split<<<16384, 256, 0, stream>>>(xs, Ahi, Alo, 4194304);
  conv_w_split<<<4096, 256, 0, stream>>>(wif, wzo, Whi, Wlo);

  for (int t0 = 0; t0 < 512; t0 += tch) {
    gemm3_kernel<<<dim3(tch / 4, 32), 256, 0, stream>>>(Ahi, Alo, Whi, Wlo,
                                                        G, t0, ltch);
    recur_kernel<<<256, 512, 0, stream>>>(G, whh, bias, out, state, t0, tch,
                                          t0 == 0);
  }
}

// Round 5
// 1032.277 us; speedup vs baseline: 1.4193x; 1.1006x over previous
//
#include <hip/hip_runtime.h>
#include <hip/hip_bf16.h>
#include <stdint.h>

// Problem dims
#define B_SZ 32
#define T_SZ 512
#define I_SZ 1024
#define H_SZ 8
#define HS_SZ 128

typedef __attribute__((ext_vector_type(8))) short short8;
typedef __attribute__((ext_vector_type(4))) float f32x4;

// ---------------- fp32 <-> bf16 helpers ----------------
static __device__ __forceinline__ unsigned short f2bf(float f) {
  union { float f; unsigned int u; } c; c.f = f;
  unsigned int u = c.u;
  unsigned int r = (u + 0x7fffu + ((u >> 16) & 1u)) >> 16;
  return (unsigned short)r;
}
static __device__ __forceinline__ float bf2f(unsigned short s) {
  union { unsigned int u; float f; } c; c.u = ((unsigned int)s) << 16;
  return c.f;
}
// split x into hi (bf16) + lo (bf16 of residual)
static __device__ __forceinline__ void split2(float x, unsigned short& hi,
                                              unsigned short& lo) {
  hi = f2bf(x);
  lo = f2bf(x - bf2f(hi));
}

__global__ void conv_x_split(const float* __restrict__ x,
                             unsigned short* __restrict__ ohi,
                             unsigned short* __restrict__ olo, int n4) {
  int i = blockIdx.x * blockDim.x + threadIdx.x;
  if (i >= n4) return;
  float4 v = ((const float4*)x)[i];
  ushort4 h, l;
  split2(v.x, h.x, l.x);
  split2(v.y, h.y, l.y);
  split2(v.z, h.z, l.z);
  split2(v.w, h.w, l.w);
  ((ushort4*)ohi)[i] = h;
  ((ushort4*)olo)[i] = l;
}

// Combined weight Wc[4096][1024], row n = h*512 + k4:
//   k4 in [0,256)   -> weight_if[h][k4][:]      (i rows then f rows)
//   k4 in [256,512) -> weight_zo[h][k4-256][:]  (z rows then o rows)
__global__ void conv_w_split(const float* __restrict__ wif,
                             const float* __restrict__ wzo,
                             unsigned short* __restrict__ ohi,
                             unsigned short* __restrict__ olo) {
  int i = blockIdx.x * blockDim.x + threadIdx.x;  // float4 index
  int flat = i * 4;
  int n = flat >> 10;
  int col = flat & 1023;
  int h = n >> 9, k4 = n & 511;
  const float* src = (k4 < 256)
                         ? (wif + ((size_t)(h * 256 + k4) * 1024 + col))
                         : (wzo + ((size_t)(h * 256 + (k4 - 256)) * 1024 + col));
  float4 v = *(const float4*)src;
  ushort4 hh, ll;
  split2(v.x, hh.x, ll.x);
  split2(v.y, hh.y, ll.y);
  split2(v.z, hh.z, ll.z);
  split2(v.w, hh.w, ll.w);
  ((ushort4*)ohi)[i] = hh;
  ((ushort4*)olo)[i] = ll;
}

// ---------------- GEMM (3-pass split bf16 = emulated fp32) ----------------
// G[32*tch x 4096] = A_chunk[32*tch x 1024] * Wc^T, acc += AhWh + AhWl + AlWh.
__device__ __forceinline__ void gld_lds16(const void* g, void* l) {
  __builtin_amdgcn_global_load_lds(
      (const __attribute__((address_space(1))) void*)g,
      (__attribute__((address_space(3))) void*)l, 16, 0, 0);
}

__global__ __launch_bounds__(256)
void gemm3_kernel(const unsigned short* __restrict__ Ahi,
                  const unsigned short* __restrict__ Alo,
                  const unsigned short* __restrict__ Whi,
                  const unsigned short* __restrict__ Wlo,
                  float* __restrict__ G, int t0, int ltch) {
  __shared__ short AH[128 * 32];
  __shared__ short AL[128 * 32];
  __shared__ short WH[128 * 32];
  __shared__ short WL[128 * 32];

  int tid = threadIdx.x;
  int lane = tid & 63, wave = tid >> 6;
  int wm = wave >> 1, wn = wave & 1;
  int bx = blockIdx.x, by = blockIdx.y;
  int l15 = lane & 15, kg = lane >> 4;
  int tchm = (1 << ltch) - 1;

  f32x4 zero4 = {0.f, 0.f, 0.f, 0.f};
  f32x4 acc[4][4];
#pragma unroll
  for (int mi = 0; mi < 4; ++mi)
#pragma unroll
    for (int ni = 0; ni < 4; ++ni) acc[mi][ni] = zero4;

  int u0 = wave * 128 + lane;
  int u1 = u0 + 64;
  int r0 = bx * 128 + (u0 >> 2);
  int r1 = bx * 128 + (u1 >> 2);
  size_t arow0 = (size_t)(r0 >> ltch) * 512 + t0 + (r0 & tchm);
  size_t arow1 = (size_t)(r1 >> ltch) * 512 + t0 + (r1 & tchm);
  size_t aoff0 = arow0 * 1024 + (u0 & 3) * 8;
  size_t aoff1 = arow1 * 1024 + (u1 & 3) * 8;
  size_t woff0 = (size_t)(by * 128 + (u0 >> 2)) * 1024 + (u0 & 3) * 8;
  size_t woff1 = (size_t)(by * 128 + (u1 >> 2)) * 1024 + (u1 & 3) * 8;

  short* ah_d0 = &AH[wave * 1024];
  short* ah_d1 = &AH[wave * 1024 + 512];
  short* al_d0 = &AL[wave * 1024];
  short* al_d1 = &AL[wave * 1024 + 512];
  short* wh_d0 = &WH[wave * 1024];
  short* wh_d1 = &WH[wave * 1024 + 512];
  short* wl_d0 = &WL[wave * 1024];
  short* wl_d1 = &WL[wave * 1024 + 512];

  for (int k0 = 0; k0 < 1024; k0 += 32) {
    __syncthreads();
    gld_lds16(Ahi + aoff0 + k0, ah_d0);
    gld_lds16(Ahi + aoff1 + k0, ah_d1);
    gld_lds16(Alo + aoff0 + k0, al_d0);
    gld_lds16(Alo + aoff1 + k0, al_d1);
    gld_lds16(Whi + woff0 + k0, wh_d0);
    gld_lds16(Whi + woff1 + k0, wh_d1);
    gld_lds16(Wlo + woff0 + k0, wl_d0);
    gld_lds16(Wlo + woff1 + k0, wl_d1);
    __syncthreads();

    short8 ah[4], al[4], wh[4], wl[4];
#pragma unroll
    for (int mi = 0; mi < 4; ++mi) {
      int ro = (wm * 64 + mi * 16 + l15) * 32 + kg * 8;
      ah[mi] = *(const short8*)&AH[ro];
      al[mi] = *(const short8*)&AL[ro];
    }
#pragma unroll
    for (int ni = 0; ni < 4; ++ni) {
      int ro = (wn * 64 + ni * 16 + l15) * 32 + kg * 8;
      wh[ni] = *(const short8*)&WH[ro];
      wl[ni] = *(const short8*)&WL[ro];
    }

#pragma unroll
    for (int mi = 0; mi < 4; ++mi)
#pragma unroll
      for (int ni = 0; ni < 4; ++ni) {
        acc[mi][ni] = __builtin_amdgcn_mfma_f32_16x16x32_bf16(
            ah[mi], wh[ni], acc[mi][ni], 0, 0, 0);
        acc[mi][ni] = __builtin_amdgcn_mfma_f32_16x16x32_bf16(
            ah[mi], wl[ni], acc[mi][ni], 0, 0, 0);
        acc[mi][ni] = __builtin_amdgcn_mfma_f32_16x16x32_bf16(
            al[mi], wh[ni], acc[mi][ni], 0, 0, 0);
      }
  }

  // C/D layout (m89-verified): col = lane&15, row = (lane>>4)*4 + reg
#pragma unroll
  for (int mi = 0; mi < 4; ++mi)
#pragma unroll
    for (int ni = 0; ni < 4; ++ni)
#pragma unroll
      for (int r = 0; r < 4; ++r) {
        int grow = bx * 128 + wm * 64 + mi * 16 + kg * 4 + r;
        int gcol = by * 128 + wn * 64 + ni * 16 + l15;
        G[(size_t)grow * 4096 + gcol] = acc[mi][ni][r];
      }
}

// ---------------- Recurrence ----------------
// 256 blocks (one per (b,h)) x 512 threads (8 waves).
// Thread t = p*128 + e owns the 32-col slice [32p,32p+32) of W_hh rows
// {e,128+e,256+e,384+e} as 128 SCALAR fp32 VGPRs.
//
// Round-4 lesson: __launch_bounds__(512,2) was interpreted as 2 blocks/CU
// -> 4 waves/EU -> 128-VGPR cap -> the 128-reg weight array was spilled
// (VGPR_Count=84, step time unchanged, L2-BW-bound on W refetch).
// Fix: (512,1) -> >=256-VGPR budget (actual occupancy was 1 block/CU
// anyway), plus flat scalar array + per-scalar asm pin so nothing blocks
// SROA. Success criterion: VGPR_Count >= ~140.
static __device__ __forceinline__ float dot4(float4 a, float4 b, float acc) {
  acc = fmaf(a.x, b.x, acc);
  acc = fmaf(a.y, b.y, acc);
  acc = fmaf(a.z, b.z, acc);
  acc = fmaf(a.w, b.w, acc);
  return acc;
}

__global__ __launch_bounds__(512, 1)
void recur_kernel(const float* __restrict__ G,     // [32*tch, 4096] chunk
                  const float* __restrict__ Whh,   // [8,512,128]
                  const float* __restrict__ bias,  // [8,512]
                  float* __restrict__ out,         // [32,512,1024]
                  float* __restrict__ state,       // 4 x [32,8,128]
                  int t0, int tch, int first) {
  int blk = blockIdx.x;
  int b = blk >> 3, h = blk & 7;
  int t = threadIdx.x;
  int e = t & 127;  // element
  int p = t >> 7;   // col-slice

  __shared__ __align__(16) float hbuf[2][128];
  __shared__ float part_s[4][4][128];  // [gate][p][e]

  // own W slice as 128 scalars: wreg[g*32 + c] = W_hh[h][g*128+e][32p + c]
  float wreg[128];
  const float* wbase = Whh + (size_t)h * 65536 + (size_t)p * 32;
#pragma unroll
  for (int g = 0; g < 4; ++g) {
    const float4* wp = (const float4*)(wbase + (size_t)(g * 128 + e) * 128);
#pragma unroll
    for (int q = 0; q < 8; ++q) {
      float4 v = wp[q];
      wreg[g * 32 + q * 4 + 0] = v.x;
      wreg[g * 32 + q * 4 + 1] = v.y;
      wreg[g * 32 + q * 4 + 2] = v.z;
      wreg[g * 32 + q * 4 + 3] = v.w;
    }
  }
#pragma unroll
  for (int i = 0; i < 128; ++i)
    asm volatile("" : "+v"(wreg[i]));  // opaque def: not remat-able

  float c_r = 0.f, n_r = 0.f, m_r = 0.f;
  int si = (b * 8 + h) * 128 + e;
  float bj0 = 0.f, bj1 = 0.f, bj2 = 0.f, bj3 = 0.f;
  float gc0 = 0.f, gc1 = 0.f, gc2 = 0.f, gc3 = 0.f;
  const float* gpb = G + (size_t)(b * tch) * 4096 + h * 512 + e;
  float* op = out + ((size_t)b * 512 + t0) * 1024 + h * 128 + e;

  if (t < 128) {
    float h0 = 0.f;
    if (!first) {
      h0 = state[si];
      c_r = state[32768 + si];
      m_r = state[65536 + si];
      n_r = state[98304 + si];
    }
    hbuf[0][e] = h0;
    bj0 = bias[h * 512 + e];
    bj1 = bias[h * 512 + 128 + e];
    bj2 = bias[h * 512 + 256 + e];
    bj3 = bias[h * 512 + 384 + e];
    gc0 = gpb[0];
    gc1 = gpb[128];
    gc2 = gpb[256];
    gc3 = gpb[384];
  }
  __syncthreads();

  int cur = 0;
  for (int s = 0; s < tch; ++s) {
    // ---- matvec phase (all 512 threads); h reads are wave-uniform ----
    const float4* hv = (const float4*)&hbuf[cur][p * 32];
    float a0 = 0.f, a1 = 0.f, a2 = 0.f, a3 = 0.f;
#pragma unroll
    for (int q = 0; q < 8; ++q) {
      float4 h4 = hv[q];
      a0 = fmaf(wreg[q * 4 + 0], h4.x, a0);
      a0 = fmaf(wreg[q * 4 + 1], h4.y, a0);
      a0 = fmaf(wreg[q * 4 + 2], h4.z, a0);
      a0 = fmaf(wreg[q * 4 + 3], h4.w, a0);
      a1 = fmaf(wreg[32 + q * 4 + 0], h4.x, a1);
      a1 = fmaf(wreg[32 + q * 4 + 1], h4.y, a1);
      a1 = fmaf(wreg[32 + q * 4 + 2], h4.z, a1);
      a1 = fmaf(wreg[32 + q * 4 + 3], h4.w, a1);
      a2 = fmaf(wreg[64 + q * 4 + 0], h4.x, a2);
      a2 = fmaf(wreg[64 + q * 4 + 1], h4.y, a2);
      a2 = fmaf(wreg[64 + q * 4 + 2], h4.z, a2);
      a2 = fmaf(wreg[64 + q * 4 + 3], h4.w, a2);
      a3 = fmaf(wreg[96 + q * 4 + 0], h4.x, a3);
      a3 = fmaf(wreg[96 + q * 4 + 1], h4.y, a3);
      a3 = fmaf(wreg[96 + q * 4 + 2], h4.z, a3);
      a3 = fmaf(wreg[96 + q * 4 + 3], h4.w, a3);
    }
    part_s[0][p][e] = a0;
    part_s[1][p][e] = a1;
    part_s[2][p][e] = a2;
    part_s[3][p][e] = a3;
    __syncthreads();

    // ---- gate phase (threads 0..127) ----
    if (t < 128) {
      // prefetch next step's G (consumed next iteration)
      float gn0 = 0.f, gn1 = 0.f, gn2 = 0.f, gn3 = 0.f;
      if (s + 1 < tch) {
        const float* gnp = gpb + (size_t)(s + 1) * 4096;
        gn0 = gnp[0];
        gn1 = gnp[128];
        gn2 = gnp[256];
        gn3 = gnp[384];
      }
      float iv = bj0 + gc0 + ((part_s[0][0][e] + part_s[0][1][e]) +
                              (part_s[0][2][e] + part_s[0][3][e]));
      float fv = bj1 + gc1 + ((part_s[1][0][e] + part_s[1][1][e]) +
                              (part_s[1][2][e] + part_s[1][3][e]));
      float zv = bj2 + gc2 + ((part_s[2][0][e] + part_s[2][1][e]) +
                              (part_s[2][2][e] + part_s[2][3][e]));
      float ov = bj3 + gc3 + ((part_s[3][0][e] + part_s[3][1][e]) +
                              (part_s[3][2][e] + part_s[3][3][e]));
      float e2 = __expf(2.f * zv);
      float zt = 1.f - 2.f / (e2 + 1.f);       // tanh, inf-safe
      float og = 1.f / (1.f + __expf(-ov));    // sigmoid
      float mn = fmaxf(fv + m_r, iv);
      float ie = __expf(iv - mn);
      float fe = __expf(fv + m_r - mn);
      c_r = fe * c_r + ie * zt;
      n_r = fe * n_r + ie;
      m_r = mn;
      float hnew = og * (c_r / n_r);
      hbuf[cur ^ 1][e] = hnew;
      op[(size_t)s * 1024] = hnew;
      gc0 = gn0; gc1 = gn1; gc2 = gn2; gc3 = gn3;
    }
    __syncthreads();
    cur ^= 1;
  }

  if (t < 128) {
    state[si] = hbuf[cur][e];
    state[32768 + si] = c_r;
    state[65536 + si] = m_r;
    state[98304 + si] = n_r;
  }
}

// ---------------- launch ----------------
extern "C" void kernel_launch(void* const* d_in, const int* in_sizes, int n_in,
                              void* d_out, int out_size, void* d_ws, size_t ws_size,
                              hipStream_t stream) {
  const float* xs   = (const float*)d_in[0];
  const float* wif  = (const float*)d_in[1];
  const float* wzo  = (const float*)d_in[2];
  const float* whh  = (const float*)d_in[3];
  const float* bias = (const float*)d_in[4];
  float* out = (float*)d_out;

  char* ws = (char*)d_ws;
  unsigned short* Ahi = (unsigned short*)ws;                 // 33,554,432 B
  unsigned short* Alo = (unsigned short*)(ws + 33554432);    // 33,554,432 B
  unsigned short* Whi = (unsigned short*)(ws + 67108864);    //  8,388,608 B
  unsigned short* Wlo = (unsigned short*)(ws + 75497472);    //  8,388,608 B
  const size_t gbase = 83886080;

  // adaptive time chunk so G fits in ws
  int tch = 128;
  while (tch > 8 &&
         gbase + (size_t)32 * tch * 4096 * 4 + 524288 > ws_size)
    tch >>= 1;
  int ltch = (tch == 128) ? 7 : (tch == 64) ? 6 : (tch == 32) ? 5
             : (tch == 16) ? 4 : 3;

  float* G = (float*)(ws + gbase);
  float* state = (float*)(ws + gbase + (size_t)32 * tch * 4096 * 4);

  conv_x_split<<<16384, 256, 0, stream>>>(xs, Ahi, Alo, 4194304);
  conv_w_split<<<4096, 256, 0, stream>>>(wif, wzo, Whi, Wlo);

  for (int t0 = 0; t0 < 512; t0 += tch) {
    gemm3_kernel<<<dim3(tch / 4, 32), 256, 0, stream>>>(Ahi, Alo, Whi, Wlo,
                                                        G, t0, ltch);
    recur_kernel<<<256, 512, 0, stream>>>(G, whh, bias, out, state, t0, tch,
                                          t0 == 0);
  }
}